// Round 8
// baseline (398.126 us; speedup 1.0000x reference)
//
#include <hip/hip_runtime.h>
#include <math.h>

// Problem constants (from reference setup_inputs)
#define B_     8
#define H_     32
#define D_     128
#define SMAX_  4096
#define HD_    (H_ * D_)     // 4096 floats = 16 KB per position
#define SCALE  0.5f
#define CHUNK  8             // consecutive positions per block -> 128 KB/stream
#define NCHUNK (SMAX_ / CHUNK)   // 512
#define PSTRIDE 132          // record: acc[128], m, l, pad2 (16B-aligned)

// ---------------------------------------------------------------------------
// Kernel 1: flash-decode partials, FULLY-SEQUENTIAL streams.
// grid = NCHUNK * B = 4096 blocks (b fastest -> inactive high-c blocks are
// dispatched last), 256 threads. Block (b, c) handles positions
// [8c, 8c+8) for ALL 32 heads: it reads kcache[b, 8c:8c+8, :, :] =
// 128 KB fully contiguous (and same for V). Thread t owns head t>>3,
// d-slice (t&7)*16 (16 floats = 64 B contiguous per position).
// Dot reduced over 8-lane clusters; online softmax replicated in cluster.
// Inactive blocks (8c > sl) write only the (m,l)=(-1e30,0) header.
// ---------------------------------------------------------------------------
__global__ void attn_partial(const float* __restrict__ q,
                             const float* __restrict__ knew,
                             const float* __restrict__ vnew,
                             const float* __restrict__ kcache,
                             const float* __restrict__ vcache,
                             const int* __restrict__ seqlen,
                             float* __restrict__ ws)
{
    const int blk = blockIdx.x;
    const int b   = blk & (B_ - 1);
    const int c   = blk >> 3;
    const int t   = threadIdx.x;
    const int h   = t >> 3;
    const int ds  = (t & 7) * 16;

    const int sl    = seqlen[b];
    const int total = sl + 1;                  // positions 0..sl (sl = new token)
    const int cs    = c * CHUNK;
    const int ce    = min(cs + CHUNK, total);

    float* wsp = ws + (((size_t)b * NCHUNK + c) * H_ + h) * PSTRIDE;

    if (cs >= ce) {                            // chunk beyond sequence: header only
        if ((t & 7) == 0) { wsp[128] = -1e30f; wsp[129] = 0.f; }
        return;
    }

    // q fragment: 16 floats
    float qf[16];
    {
        const float* qp = q + (b * H_ + h) * D_ + ds;
        float4 t0 = *(const float4*)(qp);
        float4 t1 = *(const float4*)(qp + 4);
        float4 t2 = *(const float4*)(qp + 8);
        float4 t3 = *(const float4*)(qp + 12);
        qf[0]=t0.x;  qf[1]=t0.y;  qf[2]=t0.z;  qf[3]=t0.w;
        qf[4]=t1.x;  qf[5]=t1.y;  qf[6]=t1.z;  qf[7]=t1.w;
        qf[8]=t2.x;  qf[9]=t2.y;  qf[10]=t2.z; qf[11]=t2.w;
        qf[12]=t3.x; qf[13]=t3.y; qf[14]=t3.z; qf[15]=t3.w;
    }

    float m = -1e30f, l = 0.f;                 // -1e30 sentinel, NOT -inf
    float acc[16];
    #pragma unroll
    for (int j = 0; j < 16; ++j) acc[j] = 0.f;

// one position from pointers KP/VP (16 floats = 64 B contiguous per thread)
#define STEP1(KP, VP) do {                                                    \
    float4 k0 = *(const float4*)(KP);                                         \
    float4 k1 = *(const float4*)((KP)+4);                                     \
    float4 k2 = *(const float4*)((KP)+8);                                     \
    float4 k3 = *(const float4*)((KP)+12);                                    \
    float4 v0 = *(const float4*)(VP);                                         \
    float4 v1 = *(const float4*)((VP)+4);                                     \
    float4 v2 = *(const float4*)((VP)+8);                                     \
    float4 v3 = *(const float4*)((VP)+12);                                    \
    float s = qf[0]*k0.x+qf[1]*k0.y+qf[2]*k0.z+qf[3]*k0.w                     \
            + qf[4]*k1.x+qf[5]*k1.y+qf[6]*k1.z+qf[7]*k1.w                     \
            + qf[8]*k2.x+qf[9]*k2.y+qf[10]*k2.z+qf[11]*k2.w                   \
            + qf[12]*k3.x+qf[13]*k3.y+qf[14]*k3.z+qf[15]*k3.w;                \
    s += __shfl_xor(s, 1); s += __shfl_xor(s, 2); s += __shfl_xor(s, 4);      \
    s *= SCALE;                                                               \
    float mn = fmaxf(m, s);                                                   \
    float sc = __expf(m - mn);                                                \
    float pr = __expf(s - mn);                                                \
    m = mn; l = l * sc + pr;                                                  \
    acc[0]=fmaf(pr,v0.x,acc[0]*sc);  acc[1]=fmaf(pr,v0.y,acc[1]*sc);          \
    acc[2]=fmaf(pr,v0.z,acc[2]*sc);  acc[3]=fmaf(pr,v0.w,acc[3]*sc);          \
    acc[4]=fmaf(pr,v1.x,acc[4]*sc);  acc[5]=fmaf(pr,v1.y,acc[5]*sc);          \
    acc[6]=fmaf(pr,v1.z,acc[6]*sc);  acc[7]=fmaf(pr,v1.w,acc[7]*sc);          \
    acc[8]=fmaf(pr,v2.x,acc[8]*sc);  acc[9]=fmaf(pr,v2.y,acc[9]*sc);          \
    acc[10]=fmaf(pr,v2.z,acc[10]*sc);acc[11]=fmaf(pr,v2.w,acc[11]*sc);        \
    acc[12]=fmaf(pr,v3.x,acc[12]*sc);acc[13]=fmaf(pr,v3.y,acc[13]*sc);        \
    acc[14]=fmaf(pr,v3.z,acc[14]*sc);acc[15]=fmaf(pr,v3.w,acc[15]*sc);        \
} while (0)

    const size_t base = (size_t)b * SMAX_ * HD_ + (size_t)cs * HD_ + (size_t)t * 16;
    const float* kp = kcache + base;
    const float* vp = vcache + base;

    const int pend = min(ce, sl);              // cache-resident part
    for (int p = cs; p < pend; ++p) {
        STEP1(kp, vp);
        kp += HD_;
        vp += HD_;
    }
    // appended token (position sl) from knew/vnew, if inside this chunk
    if (sl >= cs && sl < ce) {
        const float* kn = knew + (size_t)b * HD_ + t * 16;
        const float* vn = vnew + (size_t)b * HD_ + t * 16;
        STEP1(kn, vn);
    }
#undef STEP1

    // write partial record: {acc[128], m, l} per (b, c, h)
    if ((t & 7) == 0) { wsp[128] = m; wsp[129] = l; }
    float* op = wsp + ds;
    *(float4*)(op)      = make_float4(acc[0],  acc[1],  acc[2],  acc[3]);
    *(float4*)(op + 4)  = make_float4(acc[4],  acc[5],  acc[6],  acc[7]);
    *(float4*)(op + 8)  = make_float4(acc[8],  acc[9],  acc[10], acc[11]);
    *(float4*)(op + 12) = make_float4(acc[12], acc[13], acc[14], acc[15]);
}

// ---------------------------------------------------------------------------
// Kernel 2: combine partials. grid = B*H blocks, 128 threads.
// Phase 1: threads strided over chunks -> block max(m), lt, weights in LDS.
// Phase 2: thread t = dim d -> a_d = sum_c e_c * acc[c][d], skipping e==0
// (uniform branch; saves reading acc of empty chunks).
// ---------------------------------------------------------------------------
__global__ __launch_bounds__(128)
void attn_combine(const float* __restrict__ ws, float* __restrict__ out)
{
    const int bh = blockIdx.x;
    const int b  = bh >> 5;          // / H_
    const int h  = bh & (H_ - 1);
    const int t  = threadIdx.x;

    __shared__ float sm_e[NCHUNK];
    __shared__ float sm_w[2];

    const size_t sstride = (size_t)H_ * PSTRIDE;
    const float* base = ws + ((size_t)b * NCHUNK * H_ + h) * PSTRIDE;

    // phase 1a: max of m over chunks
    float mx = -1e30f;
    for (int s = t; s < NCHUNK; s += 128) mx = fmaxf(mx, base[(size_t)s * sstride + 128]);
    #pragma unroll
    for (int off = 1; off < 64; off <<= 1) mx = fmaxf(mx, __shfl_xor(mx, off));
    if ((t & 63) == 0) sm_w[t >> 6] = mx;
    __syncthreads();
    const float mt = fmaxf(sm_w[0], sm_w[1]);
    __syncthreads();                                   // before sm_w reuse

    // phase 1b: per-chunk weights e_c and lt
    float le = 0.f;
    for (int s = t; s < NCHUNK; s += 128) {
        const float* p = base + (size_t)s * sstride;
        float ms = p[128], ls = p[129];
        float e = (ls > 0.f) ? __expf(ms - mt) : 0.f;  // empty chunk -> weight 0
        sm_e[s] = e;
        le += ls * e;
    }
    #pragma unroll
    for (int off = 1; off < 64; off <<= 1) le += __shfl_xor(le, off);
    if ((t & 63) == 0) sm_w[t >> 6] = le;
    __syncthreads();
    const float lt = sm_w[0] + sm_w[1];

    // phase 2: accumulate dimension t across chunks with data
    const float* ab = base + t;
    float a = 0.f;
    for (int s = 0; s < NCHUNK; ++s) {
        float e = sm_e[s];
        if (e != 0.f) {                                // uniform across block
            a += e * ab[(size_t)s * sstride];
        }
    }
    out[bh * D_ + t] = a / lt;
}

extern "C" void kernel_launch(void* const* d_in, const int* in_sizes, int n_in,
                              void* d_out, int out_size, void* d_ws, size_t ws_size,
                              hipStream_t stream) {
    const float* q  = (const float*)d_in[0];
    const float* k  = (const float*)d_in[1];
    const float* v  = (const float*)d_in[2];
    const float* kc = (const float*)d_in[3];
    const float* vc = (const float*)d_in[4];
    const int*   sl = (const int*)d_in[5];
    float* out = (float*)d_out;
    float* ws  = (float*)d_ws;

    // ws need: 8*512*32*132*4 = ~69 MB (d_ws is ~2 GB per harness fills)
    attn_partial<<<NCHUNK * B_, 256, 0, stream>>>(q, k, v, kc, vc, sl, ws);
    attn_combine<<<B_ * H_, 128, 0, stream>>>(ws, out);
}

// Round 9
// 140.584 us; speedup vs baseline: 2.8319x; 2.8319x over previous
//
#include <hip/hip_runtime.h>
#include <math.h>

// Problem constants (from reference setup_inputs)
#define B_    8
#define H_    32
#define D_    128
#define SMAX_ 4096
#define SCALE 0.5f

// Flash-decode partial kernel.
// grid = B*H*nsplit blocks, 256 threads (4 waves).
// Each 16-lane group processes one key position at a time:
//   lane (tid&15) owns d = (tid&15)*8 .. +7  (two float4 loads, 512B/group coalesced)
// Online softmax per group -> shfl merge across groups -> LDS merge across waves.
// Writes partial (m, l, acc[128]) per (bh, split) to ws, or final out if nsplit==1.
//
// NOTE (R9): this is the empirically best structure of 7 tried (139.6 us).
// All alternatives (16KB bursts, 4KB granules, dense streams, nt loads)
// land at 3.7-4.2 TB/s effective read BW -> structural read-path ceiling.
__global__ __launch_bounds__(256, 4)
void attn_partial(const float* __restrict__ q,
                  const float* __restrict__ knew,
                  const float* __restrict__ vnew,
                  const float* __restrict__ kcache,
                  const float* __restrict__ vcache,
                  const int* __restrict__ seqlen,
                  float* __restrict__ ws,
                  float* __restrict__ out,
                  int nsplit, int chunk)
{
    const int blk   = blockIdx.x;
    const int split = blk % nsplit;
    const int bh    = blk / nsplit;
    const int h     = bh & (H_ - 1);
    const int b     = bh / H_;

    const int sl    = seqlen[b];
    const int total = sl + 1;                 // attend positions 0..sl (sl == new token)
    const int cs    = split * chunk;
    const int ce    = min(cs + chunk, total);

    const int tid    = threadIdx.x;
    const int lane16 = tid & 15;              // d-slice owner within group
    const int gid    = tid >> 4;              // 0..15 position-group id within block

    // q fragment: 8 floats per lane
    const int qbase = (b * H_ + h) * D_ + lane16 * 8;
    float qf[8];
    {
        float4 q0 = *(const float4*)(q + qbase);
        float4 q1 = *(const float4*)(q + qbase + 4);
        qf[0]=q0.x; qf[1]=q0.y; qf[2]=q0.z; qf[3]=q0.w;
        qf[4]=q1.x; qf[5]=q1.y; qf[6]=q1.z; qf[7]=q1.w;
    }

    // -1e30 sentinel (NOT -inf: exp(-inf - -inf) = NaN when merging empty groups)
    float m = -1e30f, l = 0.f;
    float acc[8];
    #pragma unroll
    for (int j = 0; j < 8; ++j) acc[j] = 0.f;

    const size_t cbase = (size_t)b * SMAX_ * (H_ * D_) + (size_t)h * D_ + (size_t)(lane16 * 8);

    for (int p = cs + gid; p < ce; p += 16) {
        const float* kp;
        const float* vp;
        if (p == sl) {                       // the appended token comes from k/v inputs
            kp = knew + qbase;
            vp = vnew + qbase;
        } else {
            size_t off = cbase + (size_t)p * (H_ * D_);
            kp = kcache + off;
            vp = vcache + off;
        }
        float4 k0 = *(const float4*)(kp);
        float4 k1 = *(const float4*)(kp + 4);
        float4 v0 = *(const float4*)(vp);
        float4 v1 = *(const float4*)(vp + 4);

        float s = qf[0]*k0.x + qf[1]*k0.y + qf[2]*k0.z + qf[3]*k0.w
                + qf[4]*k1.x + qf[5]*k1.y + qf[6]*k1.z + qf[7]*k1.w;
        // reduce partial dot across the 16-lane group
        s += __shfl_xor(s, 1);
        s += __shfl_xor(s, 2);
        s += __shfl_xor(s, 4);
        s += __shfl_xor(s, 8);
        s *= SCALE;

        float mn = fmaxf(m, s);
        float sc = __expf(m - mn);
        float pr = __expf(s - mn);
        m = mn;
        l = l * sc + pr;
        acc[0] = fmaf(pr, v0.x, acc[0]*sc);
        acc[1] = fmaf(pr, v0.y, acc[1]*sc);
        acc[2] = fmaf(pr, v0.z, acc[2]*sc);
        acc[3] = fmaf(pr, v0.w, acc[3]*sc);
        acc[4] = fmaf(pr, v1.x, acc[4]*sc);
        acc[5] = fmaf(pr, v1.y, acc[5]*sc);
        acc[6] = fmaf(pr, v1.z, acc[6]*sc);
        acc[7] = fmaf(pr, v1.w, acc[7]*sc);
    }

    // merge the 4 groups within each wave (lanes with equal (tid&15) hold same d-slice)
    #pragma unroll
    for (int off = 16; off <= 32; off <<= 1) {
        float m2 = __shfl_xor(m, off);
        float l2 = __shfl_xor(l, off);
        float a2[8];
        #pragma unroll
        for (int j = 0; j < 8; ++j) a2[j] = __shfl_xor(acc[j], off);
        float mn = fmaxf(m, m2);
        float s1 = __expf(m - mn);
        float s2 = __expf(m2 - mn);
        l = l * s1 + l2 * s2;
        #pragma unroll
        for (int j = 0; j < 8; ++j) acc[j] = acc[j]*s1 + a2[j]*s2;
        m = mn;
    }

    // merge the 4 waves via LDS
    __shared__ float sm_m[4];
    __shared__ float sm_l[4];
    __shared__ float sm_acc[4][D_];
    const int w    = tid >> 6;
    const int lane = tid & 63;
    if (lane < 16) {
        if (lane == 0) { sm_m[w] = m; sm_l[w] = l; }
        #pragma unroll
        for (int j = 0; j < 8; ++j) sm_acc[w][lane16*8 + j] = acc[j];
    }
    __syncthreads();

    if (tid < D_) {
        float m0 = sm_m[0], m1 = sm_m[1], m2 = sm_m[2], m3 = sm_m[3];
        float mt = fmaxf(fmaxf(m0, m1), fmaxf(m2, m3));
        float e0 = __expf(m0 - mt), e1 = __expf(m1 - mt);
        float e2 = __expf(m2 - mt), e3 = __expf(m3 - mt);
        float lt = sm_l[0]*e0 + sm_l[1]*e1 + sm_l[2]*e2 + sm_l[3]*e3;
        float a  = sm_acc[0][tid]*e0 + sm_acc[1][tid]*e1
                 + sm_acc[2][tid]*e2 + sm_acc[3][tid]*e3;
        if (nsplit == 1) {
            out[bh * D_ + tid] = a / lt;     // lt >= exp(0) contribution; total>=1 always
        } else {
            float* wsp = ws + (size_t)blk * (D_ + 2);
            if (tid == 0) { wsp[0] = mt; wsp[1] = lt; }
            wsp[2 + tid] = a;
        }
    }
}

// Combine partials across splits. grid = B*H blocks, 128 threads.
__global__ __launch_bounds__(128)
void attn_combine(const float* __restrict__ ws, float* __restrict__ out, int nsplit)
{
    const int bh = blockIdx.x;
    const int d  = threadIdx.x;
    const float* base = ws + (size_t)bh * nsplit * (D_ + 2);

    float mt = -1e30f;
    for (int s = 0; s < nsplit; ++s) mt = fmaxf(mt, base[(size_t)s * (D_ + 2)]);
    float lt = 0.f, a = 0.f;
    for (int s = 0; s < nsplit; ++s) {
        const float* p = base + (size_t)s * (D_ + 2);
        float e = __expf(p[0] - mt);
        lt += p[1] * e;
        a  += p[2 + d] * e;
    }
    out[bh * D_ + d] = a / lt;
}

extern "C" void kernel_launch(void* const* d_in, const int* in_sizes, int n_in,
                              void* d_out, int out_size, void* d_ws, size_t ws_size,
                              hipStream_t stream) {
    const float* q  = (const float*)d_in[0];
    const float* k  = (const float*)d_in[1];
    const float* v  = (const float*)d_in[2];
    const float* kc = (const float*)d_in[3];
    const float* vc = (const float*)d_in[4];
    const int*   sl = (const int*)d_in[5];
    float* out = (float*)d_out;
    float* ws  = (float*)d_ws;

    // split-K factor: 16 gives 4096 blocks (good occupancy vs only 256 for unsplit)
    int nsplit = 16;
    while (nsplit > 1 &&
           (size_t)B_ * H_ * nsplit * (D_ + 2) * sizeof(float) > ws_size) {
        nsplit >>= 1;
    }
    const int chunk = (SMAX_ + nsplit - 1) / nsplit;
    const int nblk  = B_ * H_ * nsplit;

    attn_partial<<<nblk, 256, 0, stream>>>(q, k, v, kc, vc, sl, ws, out, nsplit, chunk);
    if (nsplit > 1) {
        attn_combine<<<B_ * H_, 128, 0, stream>>>(ws, out, nsplit);
    }
}